// Round 15
// baseline (117.590 us; speedup 1.0000x reference)
//
#include <hip/hip_runtime.h>
#include <stdint.h>

#define BATCH     10000
#define NUM_TREES 1000
#define NUM_NODES 511
#define NFEAT     256
#define DEPTH     8
#define FLAT_NODES (NUM_TREES * NUM_NODES)

// ---------------- 2-level fused record layout in d_ws ----------------
// Implicit depth-8 tree. Records at even depths {0,2,4,6}:
//   rec = {f32 thr_p, f32 thr_l, f32 thr_r, u32 f_p|f_l<<8|f_r<<16}
// rec index = EBASE[d/2] + local, EBASE = {0,1,5,21}; 85 recs = 1360 B/tree.
// Byte offsets of level-pairs: {0, 16, 80, 336}. Candidates for the next
// level-pair live at eoff(it+1) + 64*loc (contiguous 64 B) — address known
// BEFORE the compares, so they can be speculatively loaded.
// Leaf: vleaf[local] per tree (256 f32 = 1024 B; float4 at +16*loc).
#define TREE_BYTES 1360
#define VLEAF_OFF  ((size_t)NUM_TREES * TREE_BYTES)          // 1,360,000
#define WS_NEEDED  (VLEAF_OFF + (size_t)NUM_TREES * 256 * 4) // 2,384,000
// x^T region: [256][XT_LD] f32, feat-major
#define XT_LD      10048
#define XT_OFF     WS_NEEDED
#define XT_BYTES   ((size_t)NFEAT * XT_LD * 4)               // 10,289,152
#define WS_XT      (XT_OFF + XT_BYTES)                       // 12,673,152

// ------- traverse geometry: 2 blocks/CU x 16 waves = 32 waves/CU cap -------
#define BT 32            // batch rows per block
#define TT 64            // trees per block
#define NTHREADS 1024    // 16 waves
#define XS_BYTES  (NFEAT * BT * 4)               // 32768
#define OUT_LD    67                             // bank (3r+c)%32: conflict-free
#define SH_BYTES  XS_BYTES                       // bounce aliased (8576 B used)

#define UNROLL_BLOCKS 250                        // 4 trees/block
#define TRANS_BLOCKS  (157 * 4)                  // 628

// async global->LDS copy, 16B per lane (LDS dest = uniform base + lane*16)
__device__ __forceinline__ void glds16(const void* g, void* l) {
  __builtin_amdgcn_global_load_lds(
      (const __attribute__((address_space(1))) unsigned int*)g,
      (__attribute__((address_space(3))) unsigned int*)l, 16, 0, 0);
}

// ===== fused prepack: tree BFS-unroll (blocks 0..249) + x transpose =====
__global__ __launch_bounds__(256)
void prepack_kernel(const float* __restrict__ thr,
                    const int* __restrict__ feats,
                    const int* __restrict__ lefts,
                    const int* __restrict__ rights,
                    const float* __restrict__ values,
                    const float* __restrict__ x,
                    unsigned char* __restrict__ ws) {
  __shared__ unsigned char sh[64 * 65 * 4];
  const int tid = threadIdx.x;

  if (blockIdx.x < UNROLL_BLOCKS) {
    uint16_t* n_s = (uint16_t*)sh;               // [4][512]
    const int wv = tid >> 6, lane = tid & 63;
    const int tree = blockIdx.x * 4 + wv;        // always < 1000
    const int base = tree * NUM_NODES;
    uint16_t* n = n_s + wv * 512;
    uint4* rec   = (uint4*)(ws + (size_t)tree * TREE_BYTES);
    float* vleaf = (float*)(ws + VLEAF_OFF + (size_t)tree * 1024);

    if (lane == 0) n[0] = 0;
    __syncthreads();
    const int EBASE[4] = {0, 1, 5, 21};
    #pragma unroll
    for (int d = 0; d < 8; ++d) {
      const int lvl = (1 << d) - 1, cnt = 1 << d;
      for (int i = lane; i < cnt; i += 64) {
        int p  = lvl + i;
        int np = n[p];
        int nl = lefts[base + np], nr = rights[base + np];
        n[2 * p + 1] = (uint16_t)nl;
        n[2 * p + 2] = (uint16_t)nr;
        if ((d & 1) == 0) {
          uint32_t f3 = (uint32_t)feats[base + np] |
                        ((uint32_t)feats[base + nl] << 8) |
                        ((uint32_t)feats[base + nr] << 16);
          rec[EBASE[d >> 1] + i] =
              make_uint4(__float_as_uint(thr[base + np]),
                         __float_as_uint(thr[base + nl]),
                         __float_as_uint(thr[base + nr]), f3);
        }
      }
      __syncthreads();
    }
    #pragma unroll
    for (int i = lane; i < 256; i += 64)
      vleaf[i] = values[base + n[255 + i]];
  } else {
    float (*tile)[65] = (float(*)[65])sh;
    float* xT = (float*)(ws + XT_OFF);
    const int t = blockIdx.x - UNROLL_BLOCKS;
    const int b0 = (t >> 2) * 64, f0 = (t & 3) * 64;
    const float4* xg = (const float4*)x;
    #pragma unroll
    for (int p = 0; p < 4; ++p) {
      int i = tid + p * 256;
      int r = i >> 4, c4 = i & 15;
      int gb = b0 + r;
      float4 v = (gb < BATCH) ? xg[(size_t)gb * 64 + (f0 >> 2) + c4]
                              : make_float4(0.f, 0.f, 0.f, 0.f);
      tile[r][4 * c4 + 0] = v.x;
      tile[r][4 * c4 + 1] = v.y;
      tile[r][4 * c4 + 2] = v.z;
      tile[r][4 * c4 + 3] = v.w;
    }
    __syncthreads();
    #pragma unroll
    for (int p = 0; p < 4; ++p) {
      int i = tid + p * 256;
      int fr = i >> 4, b4 = i & 15;
      float4 w = make_float4(tile[4 * b4 + 0][fr], tile[4 * b4 + 1][fr],
                             tile[4 * b4 + 2][fr], tile[4 * b4 + 3][fr]);
      *(float4*)(xT + (size_t)(f0 + fr) * XT_LD + b0 + 4 * b4) = w;
    }
  }
}

// ================= main traversal (speculative-children) =================
// Per iteration, per slot: issue {3 x-gathers (LDS)} and {64 B candidate
// block (global, L2-hot)} CONCURRENTLY — the candidate address depends only
// on loc, not on the compares. After the waits, pick the next record with
// cndmask chains. No dependent memory op remains in the chain.
// 16 waves x 2 slots x 2 lane-halves = 64 trees/block; lane-half = 32 rows.
template <bool XT>
__global__ __launch_bounds__(NTHREADS, 8)   // 8 waves/EU -> VGPR<=64
void traverse_spec(const float* __restrict__ x,
                   const unsigned char* __restrict__ ws,
                   float* __restrict__ out) {
  extern __shared__ unsigned char smem[];
  float* x_s   = (float*)smem;                   // [256][32]
  float* out_s = (float*)smem;                   // aliased after traversal

  const int tid  = threadIdx.x;
  const int wid  = tid >> 6;                     // 0..15
  const int lane = tid & 63;
  const int row  = lane & 31;                    // batch row in tile
  const int th   = lane >> 5;                    // tree parity
  const int b0   = blockIdx.y * BT;
  const int t0   = blockIdx.x * TT;

  // slot s -> tree t0 + 4*wid + 2*s + th
  const unsigned char* nb0 = ws + (size_t)(t0 + 4 * wid + th) * TREE_BYTES;
  const unsigned char* nb1 = nb0 + 2 * TREE_BYTES;
  uint4 r0 = *(const uint4*)nb0;                 // root records (prefetch)
  uint4 r1 = *(const uint4*)nb1;

  // ---- x staging ----
  if (XT) {
    const float* xT = (const float*)(ws + XT_OFF);
    #pragma unroll
    for (int k = 0; k < 2; ++k) {
      int fi = tid + k * NTHREADS;               // 16B chunk id, 0..2047
      int f = fi >> 3, c16 = fi & 7;             // 8 chunks per 32-f32 row
      glds16(xT + (size_t)f * XT_LD + b0 + 4 * c16,
             (unsigned char*)x_s + (size_t)fi * 16);
    }
  } else {
    const float4* xg = (const float4*)x;
    #pragma unroll
    for (int p = 0; p < 2; ++p) {
      int i = tid + p * NTHREADS;                // 0..2047
      int rr = i >> 6, c = i & 63;
      int gb = b0 + rr;
      float4 v = (gb < BATCH) ? xg[(size_t)gb * 64 + c]
                              : make_float4(0.f, 0.f, 0.f, 0.f);
      int o = (c << 7) + (rr ^ (c & 31));        // feat=4c+k at o + 32k
      x_s[o]      = v.x;
      x_s[o + 32] = v.y;
      x_s[o + 64] = v.z;
      x_s[o + 96] = v.w;
    }
  }
  __syncthreads();   // drains glds vmcnt / ds_writes

  auto xgather = [&](int f) -> float {
    if (XT) return x_s[(f << 5) + row];
    return x_s[(f << 5) + (row ^ ((f >> 2) & 31))];
  };

  const float* vl = (const float*)(ws + VLEAF_OFF);
  int g0 = t0 + 4 * wid + th, g1 = g0 + 2;
  const int gcl0 = (g0 < NUM_TREES) ? g0 : 0;
  const int gcl1 = (g1 < NUM_TREES) ? g1 : 0;

  int loc0 = 0, loc1 = 0;
  float v0 = 0.f, v1 = 0.f;
  #pragma unroll
  for (int it = 0; it < 4; ++it) {
    // issue x-gathers (LDS)
    float xp0 = xgather(r0.w & 255);
    float xl0 = xgather((r0.w >> 8) & 255);
    float xr0 = xgather((r0.w >> 16) & 255);
    float xp1 = xgather(r1.w & 255);
    float xl1 = xgather((r1.w >> 8) & 255);
    float xr1 = xgather((r1.w >> 16) & 255);
    if (it < 3) {
      // issue speculative 64 B candidate blocks (global) — overlaps LDS wait
      const int eoff = (it == 0) ? 16 : (it == 1) ? 80 : 336;
      const uint4* ca = (const uint4*)(nb0 + eoff + 64 * loc0);
      const uint4* cb = (const uint4*)(nb1 + eoff + 64 * loc1);
      uint4 a0 = ca[0], a1 = ca[1], a2 = ca[2], a3 = ca[3];
      uint4 e0 = cb[0], e1 = cb[1], e2 = cb[2], e3 = cb[3];
      bool c00 = (xp0 >= __uint_as_float(r0.x));
      float xc0 = c00 ? xr0 : xl0;
      bool c10 = (xc0 >= __uint_as_float(c00 ? r0.z : r0.y));
      bool c01 = (xp1 >= __uint_as_float(r1.x));
      float xc1 = c01 ? xr1 : xl1;
      bool c11 = (xc1 >= __uint_as_float(c01 ? r1.z : r1.y));
      uint4 sa = c00 ? a2 : a0, sb = c00 ? a3 : a1;
      r0 = c10 ? sb : sa;
      uint4 se = c01 ? e2 : e0, sf = c01 ? e3 : e1;
      r1 = c11 ? sf : se;
      loc0 = 4 * loc0 + 2 * (int)c00 + (int)c10;
      loc1 = 4 * loc1 + 2 * (int)c01 + (int)c11;
    } else {
      // last iteration: speculate the 4 candidate leaves (float4, 16 B)
      float4 lf0 = *(const float4*)(vl + (size_t)gcl0 * 256 + 4 * loc0);
      float4 lf1 = *(const float4*)(vl + (size_t)gcl1 * 256 + 4 * loc1);
      bool c00 = (xp0 >= __uint_as_float(r0.x));
      float xc0 = c00 ? xr0 : xl0;
      bool c10 = (xc0 >= __uint_as_float(c00 ? r0.z : r0.y));
      bool c01 = (xp1 >= __uint_as_float(r1.x));
      float xc1 = c01 ? xr1 : xl1;
      bool c11 = (xc1 >= __uint_as_float(c01 ? r1.z : r1.y));
      float ta = c00 ? lf0.z : lf0.x, tb = c00 ? lf0.w : lf0.y;
      v0 = c10 ? tb : ta;
      float tc = c01 ? lf1.z : lf1.x, td = c01 ? lf1.w : lf1.y;
      v1 = c10 || true ? (c11 ? td : tc) : 0.f;  // keep simple select
    }
  }

  __syncthreads();                   // all x_s reads done -> alias as out_s
  out_s[row * OUT_LD + 4 * wid + th]     = v0;   // bank (3r+c)%32: free
  out_s[row * OUT_LD + 4 * wid + 2 + th] = v1;
  __syncthreads();

  // ---- flush 32x64 tile, one 256 B coalesced segment per row ----
  #pragma unroll
  for (int k = 0; k < 2; ++k) {
    int rr = wid + 16 * k;                       // 0..31
    int col = tid & 63;
    int gb = b0 + rr, gt = t0 + col;
    if (gb < BATCH && gt < NUM_TREES)
      out[(size_t)gb * NUM_TREES + gt] = out_s[rr * OUT_LD + col];
  }
}

// ================= fallback (no-ws path) =================
#define FB_BT 64
#define FB_TT 64
#define FB_TPR 16
#define FB_NROUNDS 4
#define FB_NTHREADS 1024
#define FB_XS (NFEAT * 64 * 4)
#define FB_NSU (FB_TPR * NUM_NODES)
#define FB_NS (FB_NSU * 8)
#define FB_OLD (FB_TT + 1)
#define FB_OS (FB_BT * FB_OLD * 4)
#define FB_SH (FB_XS + FB_NS + FB_OS)
#define FB_PREF ((FB_NSU + FB_NTHREADS - 1) / FB_NTHREADS)

__global__ __launch_bounds__(FB_NTHREADS, 1)
void fb_traverse(const float* __restrict__ x,
                 const float* __restrict__ thrg,
                 const int* __restrict__ featg,
                 const int* __restrict__ leftg,
                 const int* __restrict__ rightg,
                 const float* __restrict__ values,
                 float* __restrict__ out) {
  extern __shared__ unsigned char smem[];
  float* x_s     = (float*)smem;
  uint2* nodes_s = (uint2*)(smem + FB_XS);
  float* out_s   = (float*)(smem + FB_XS + FB_NS);
  const int tid = threadIdx.x, wid = tid >> 6, lane = tid & 63;
  const int b0 = blockIdx.y * FB_BT, t0 = blockIdx.x * FB_TT;
  uint2 pf[FB_PREF];
  auto load_round = [&](int rr) {
    const int gbase = (t0 + rr * FB_TPR) * NUM_NODES;
    #pragma unroll
    for (int k = 0; k < FB_PREF; ++k) {
      int fi = tid + k * FB_NTHREADS;
      uint2 v = make_uint2(0u, 0u);
      if (fi < FB_NSU) {
        int gi = gbase + fi;
        if (gi < FLAT_NODES) {
          uint32_t meta = (uint32_t)featg[gi] | ((uint32_t)leftg[gi] << 8) |
                          ((uint32_t)rightg[gi] << 20);
          v = make_uint2(__float_as_uint(thrg[gi]), meta);
        }
      }
      pf[k] = v;
    }
  };
  auto write_nodes = [&]() {
    #pragma unroll
    for (int k = 0; k < FB_PREF; ++k) {
      int fi = tid + k * FB_NTHREADS;
      if (fi < FB_NSU) nodes_s[fi] = pf[k];
    }
  };
  load_round(0);
  {
    const float4* xg = (const float4*)x;
    #pragma unroll
    for (int p = 0; p < (FB_BT * (NFEAT / 4)) / FB_NTHREADS; ++p) {
      int i = tid + p * FB_NTHREADS;
      int r = i >> 6, c = i & 63;
      int gb = b0 + r;
      float4 v = make_float4(0.f, 0.f, 0.f, 0.f);
      if (gb < BATCH) v = xg[gb * (NFEAT / 4) + c];
      int o = (c << 8) + (r ^ (c & 31));
      x_s[o] = v.x; x_s[o + 64] = v.y; x_s[o + 128] = v.z; x_s[o + 192] = v.w;
    }
  }
  write_nodes();
  __syncthreads();
  for (int r = 0; r < FB_NROUNDS; ++r) {
    if (r + 1 < FB_NROUNDS) load_round(r + 1);
    const uint2* nA = nodes_s + wid * NUM_NODES;
    const int tr0 = t0 + r * FB_TPR;
    const int gta = tr0 + wid;
    const int offA = (gta < NUM_TREES ? gta : 0) * NUM_NODES;
    uint2 na = nA[0];
    float va = 0.f;
    #pragma unroll
    for (int d = 0; d < DEPTH; ++d) {
      int fa = na.y & 0xFF;
      int la = (na.y >> 8) & 0xFFF;
      int ra = (int)(na.y >> 20);
      float xa = x_s[(fa << 6) + (lane ^ ((fa >> 2) & 31))];
      if (d < DEPTH - 1) {
        uint2 nla = nA[la], nra = nA[ra];
        na = (xa >= __uint_as_float(na.x)) ? nra : nla;
      } else {
        float vla = values[offA + la], vra = values[offA + ra];
        va = (xa >= __uint_as_float(na.x)) ? vra : vla;
      }
    }
    out_s[lane * FB_OLD + r * FB_TPR + wid] = va;
    __syncthreads();
    if (r + 1 < FB_NROUNDS) { write_nodes(); __syncthreads(); }
  }
  {
    const int gt = t0 + lane;
    #pragma unroll
    for (int p = 0; p < FB_BT / 16; ++p) {
      int rr = p * 16 + wid;
      int gb = b0 + rr;
      if (gb < BATCH && gt < NUM_TREES)
        out[gb * NUM_TREES + gt] = out_s[rr * FB_OLD + lane];
    }
  }
}

extern "C" void kernel_launch(void* const* d_in, const int* in_sizes, int n_in,
                              void* d_out, int out_size, void* d_ws, size_t ws_size,
                              hipStream_t stream) {
  const float* x          = (const float*)d_in[0];
  const float* thresholds = (const float*)d_in[1];
  const float* values     = (const float*)d_in[2];
  const int*   lefts      = (const int*)d_in[3];
  const int*   rights     = (const int*)d_in[4];
  const int*   features   = (const int*)d_in[5];
  float* out = (float*)d_out;

  dim3 grid((NUM_TREES + TT - 1) / TT, (BATCH + BT - 1) / BT);  // 16 x 313
  if (ws_size >= WS_XT) {
    unsigned char* ws = (unsigned char*)d_ws;
    prepack_kernel<<<UNROLL_BLOCKS + TRANS_BLOCKS, 256, 0, stream>>>(
        thresholds, features, lefts, rights, values, x, ws);
    traverse_spec<true><<<grid, NTHREADS, SH_BYTES, stream>>>(x, ws, out);
  } else if (ws_size >= WS_NEEDED) {
    unsigned char* ws = (unsigned char*)d_ws;
    prepack_kernel<<<UNROLL_BLOCKS, 256, 0, stream>>>(
        thresholds, features, lefts, rights, values, x, ws);
    traverse_spec<false><<<grid, NTHREADS, SH_BYTES, stream>>>(x, ws, out);
  } else {
    hipFuncSetAttribute(reinterpret_cast<const void*>(fb_traverse),
                        hipFuncAttributeMaxDynamicSharedMemorySize, FB_SH);
    dim3 fgrid((NUM_TREES + FB_TT - 1) / FB_TT, (BATCH + FB_BT - 1) / FB_BT);
    fb_traverse<<<fgrid, FB_NTHREADS, FB_SH, stream>>>(
        x, thresholds, features, lefts, rights, values, out);
  }
}

// Round 16
// 54.977 us; speedup vs baseline: 2.1389x; 2.1389x over previous
//
#include <hip/hip_runtime.h>
#include <stdint.h>

#define BATCH     10000
#define NUM_TREES 1000
#define NUM_NODES 511
#define NFEAT     256
#define DEPTH     8
#define FLAT_NODES (NUM_TREES * NUM_NODES)

// ---------------- 2-level fused record layout in d_ws ----------------
// Implicit depth-8 tree. Records exist at even depths {0,2,4,6}:
//   rec = {f32 thr_p, f32 thr_l, f32 thr_r, u32 f_p|f_l<<8|f_r<<16}
// rec index = EBASE[d/2] + local, EBASE = {0,1,5,21}; 85 recs = 1360 B/tree.
// One b128 read descends 2 levels: local' = 4*local + 2c0 + c1.
// Leaf (depth 8): vleaf[local] per tree (256 f32 = 1024 B).
#define TREE_BYTES 1360
#define VLEAF_OFF  ((size_t)NUM_TREES * TREE_BYTES)          // 1,360,000
#define WS_NEEDED  (VLEAF_OFF + (size_t)NUM_TREES * 256 * 4) // 2,384,000
// x^T region (optional tier): [256][XT_LD] f32, feat-major
#define XT_LD      10048                                     // >= 157*64, 16B-mult
#define XT_OFF     WS_NEEDED                                 // 128-aligned
#define XT_BYTES   ((size_t)NFEAT * XT_LD * 4)               // 10,289,152
#define WS_XT      (XT_OFF + XT_BYTES)                       // 12,673,152

// ---------------- traverse geometry (2 blocks/CU, 32 waves/CU cap) ----------
#define BT 64            // batch rows per block
#define TT 64            // trees per block
#define NTHREADS 1024    // 16 waves
#define XS_BYTES  (NFEAT * 64 * 4)               // 65536
#define OUT_LD    36                             // f4-aligned, half-tile bounce
#define OS_BYTES  (64 * OUT_LD * 4)              // 9216
#define SH_BYTES  (XS_BYTES + OS_BYTES)          // 74752 <= 81920 -> 2 blocks/CU

#define UNROLL_BLOCKS 250                        // 4 trees/block
#define TRANS_BLOCKS  (157 * 4)                  // 628: 157 b-tiles x 4 f-tiles

// async global->LDS copy, 16B per lane (LDS dest = uniform base + lane*16,
// global src per-lane)
__device__ __forceinline__ void glds16(const void* g, void* l) {
  __builtin_amdgcn_global_load_lds(
      (const __attribute__((address_space(1))) unsigned int*)g,
      (__attribute__((address_space(3))) unsigned int*)l, 16, 0, 0);
}

// ===== fused prepack: tree BFS-unroll (blocks 0..249) + x transpose =====
__global__ __launch_bounds__(256)
void prepack_kernel(const float* __restrict__ thr,
                    const int* __restrict__ feats,
                    const int* __restrict__ lefts,
                    const int* __restrict__ rights,
                    const float* __restrict__ values,
                    const float* __restrict__ x,
                    unsigned char* __restrict__ ws) {
  __shared__ unsigned char sh[64 * 65 * 4];      // max(4*512*2, 64*65*4)
  const int tid = threadIdx.x;

  if (blockIdx.x < UNROLL_BLOCKS) {
    // ---------- BFS-unroll 4 trees (one per wave) ----------
    uint16_t* n_s = (uint16_t*)sh;               // [4][512]
    const int wv = tid >> 6, lane = tid & 63;
    const int tree = blockIdx.x * 4 + wv;        // always < 1000
    const int base = tree * NUM_NODES;
    uint16_t* n = n_s + wv * 512;
    uint4* rec   = (uint4*)(ws + (size_t)tree * TREE_BYTES);
    float* vleaf = (float*)(ws + VLEAF_OFF + (size_t)tree * 1024);

    if (lane == 0) n[0] = 0;
    __syncthreads();
    const int EBASE[4] = {0, 1, 5, 21};
    #pragma unroll
    for (int d = 0; d < 8; ++d) {
      const int lvl = (1 << d) - 1, cnt = 1 << d;
      for (int i = lane; i < cnt; i += 64) {
        int p  = lvl + i;
        int np = n[p];
        int nl = lefts[base + np], nr = rights[base + np];
        n[2 * p + 1] = (uint16_t)nl;
        n[2 * p + 2] = (uint16_t)nr;
        if ((d & 1) == 0) {
          uint32_t f3 = (uint32_t)feats[base + np] |
                        ((uint32_t)feats[base + nl] << 8) |
                        ((uint32_t)feats[base + nr] << 16);
          rec[EBASE[d >> 1] + i] =
              make_uint4(__float_as_uint(thr[base + np]),
                         __float_as_uint(thr[base + nl]),
                         __float_as_uint(thr[base + nr]), f3);
        }
      }
      __syncthreads();
    }
    #pragma unroll
    for (int i = lane; i < 256; i += 64)
      vleaf[i] = values[base + n[255 + i]];
  } else {
    // ---------- x -> x^T tile (64 batch x 64 feat) ----------
    float (*tile)[65] = (float(*)[65])sh;
    float* xT = (float*)(ws + XT_OFF);
    const int t = blockIdx.x - UNROLL_BLOCKS;
    const int b0 = (t >> 2) * 64, f0 = (t & 3) * 64;
    const float4* xg = (const float4*)x;
    #pragma unroll
    for (int p = 0; p < 4; ++p) {
      int i = tid + p * 256;
      int r = i >> 4, c4 = i & 15;
      int gb = b0 + r;
      float4 v = (gb < BATCH) ? xg[(size_t)gb * 64 + (f0 >> 2) + c4]
                              : make_float4(0.f, 0.f, 0.f, 0.f);
      tile[r][4 * c4 + 0] = v.x;
      tile[r][4 * c4 + 1] = v.y;
      tile[r][4 * c4 + 2] = v.z;
      tile[r][4 * c4 + 3] = v.w;
    }
    __syncthreads();
    #pragma unroll
    for (int p = 0; p < 4; ++p) {
      int i = tid + p * 256;
      int fr = i >> 4, b4 = i & 15;
      float4 w = make_float4(tile[4 * b4 + 0][fr], tile[4 * b4 + 1][fr],
                             tile[4 * b4 + 2][fr], tile[4 * b4 + 3][fr]);
      *(float4*)(xT + (size_t)(f0 + fr) * XT_LD + b0 + 4 * b4) = w;
    }
  }
}

// ================= main traversal =================
// Nodes are NOT LDS-staged (global b128 reads within one 1360 B tree region,
// L1/L2-hot, TCP path parallel to LDS gathers). XT: x staged via
// global_load_lds from feat-major x^T -> zero ds_writes; gather addr =
// (f<<6)+lane, bank = lane&31 (2-way = free) for every access.
// Speculative 2-level step: rec b128 -> {xp,xl,xr} issued together -> pick
// in regs (no serial gather hop). it0 recs prefetched before the barrier.
template <bool XT>
__global__ __launch_bounds__(NTHREADS, 8)   // 8 waves/EU = 2 blocks/CU
void traverse64(const float* __restrict__ x,
                const unsigned char* __restrict__ ws,
                float* __restrict__ out) {
  extern __shared__ unsigned char smem[];
  float* x_s   = (float*)smem;                   // [256][64]
  float* out_s = (float*)(smem + XS_BYTES);      // [64][OUT_LD] half-tile

  const int tid  = threadIdx.x;
  const int wid  = tid >> 6;
  const int lane = tid & 63;
  const int b0   = blockIdx.y * BT;
  const int t0   = blockIdx.x * TT;

  // ---- prefetch it0 records (addresses static, no LDS dep) ----
  const unsigned char* nb = ws + (size_t)(t0 + 4 * wid) * TREE_BYTES;
  uint4 r[4];
  #pragma unroll
  for (int c = 0; c < 4; ++c)
    r[c] = *(const uint4*)(nb + (size_t)c * TREE_BYTES);

  if (XT) {
    // ---- x staging: async glds from x^T rows (linear LDS, no ds_writes) ----
    const float* xT = (const float*)(ws + XT_OFF);
    #pragma unroll
    for (int k = 0; k < 4; ++k) {
      int fi = tid + k * NTHREADS;               // 16B chunk id, 0..4095
      int f = fi >> 4, c16 = fi & 15;
      glds16(xT + (size_t)f * XT_LD + b0 + 4 * c16,
             (unsigned char*)x_s + (size_t)fi * 16);
    }
  } else {
    // ---- x staging: coalesced f4 reads; swizzled conflict-free writes ----
    const float4* xg = (const float4*)x;
    #pragma unroll
    for (int p = 0; p < 4; ++p) {
      int i = tid + p * NTHREADS;
      int rr = i >> 6, c = i & 63;
      int gb = b0 + rr;
      float4 v = (gb < BATCH) ? xg[(size_t)gb * 64 + c]
                              : make_float4(0.f, 0.f, 0.f, 0.f);
      int o = (c << 8) + (rr ^ (c & 31));
      x_s[o]       = v.x;
      x_s[o + 64]  = v.y;
      x_s[o + 128] = v.z;
      x_s[o + 192] = v.w;
    }
  }
  __syncthreads();   // drains glds vmcnt + x_s writes

  auto xgather = [&](int f) -> float {
    if (XT) return x_s[(f << 6) + lane];
    return x_s[(f << 6) + (lane ^ ((f >> 2) & 31))];
  };

  // ---- traverse: wave owns 4 trees (ILP=4); lane = batch row ----
  int loc[4] = {0, 0, 0, 0};
  #pragma unroll
  for (int it = 0; it < 4; ++it) {
    float xp[4], xl[4], xr[4];
    #pragma unroll
    for (int c = 0; c < 4; ++c) {
      xp[c] = xgather(r[c].w & 255);
      xl[c] = xgather((r[c].w >> 8) & 255);
      xr[c] = xgather((r[c].w >> 16) & 255);
    }
    #pragma unroll
    for (int c = 0; c < 4; ++c) {
      bool c0  = (xp[c] >= __uint_as_float(r[c].x));
      float xc = c0 ? xr[c] : xl[c];
      float tc = __uint_as_float(c0 ? r[c].z : r[c].y);
      loc[c] = 4 * loc[c] + 2 * (int)c0 + (int)(xc >= tc);
    }
    if (it < 3) {
      const int eoff = (it == 0) ? 16 : (it == 1) ? 80 : 336;
      #pragma unroll
      for (int c = 0; c < 4; ++c)
        r[c] = *(const uint4*)(nb + (size_t)c * TREE_BYTES + loc[c] * 16 + eoff);
    }
  }
  // ---- leaf values from prepacked table (L2-resident, 1 MB) ----
  const float* vl = (const float*)(ws + VLEAF_OFF);
  float4 v;
  {
    const int gt0 = t0 + 4 * wid;
    int g0 = (gt0 + 0 < NUM_TREES) ? gt0 + 0 : 0;
    int g1 = (gt0 + 1 < NUM_TREES) ? gt0 + 1 : 0;
    int g2 = (gt0 + 2 < NUM_TREES) ? gt0 + 2 : 0;
    int g3 = (gt0 + 3 < NUM_TREES) ? gt0 + 3 : 0;
    v = make_float4(vl[(size_t)g0 * 256 + loc[0]],
                    vl[(size_t)g1 * 256 + loc[1]],
                    vl[(size_t)g2 * 256 + loc[2]],
                    vl[(size_t)g3 * 256 + loc[3]]);
  }

  // ---- out bounce, two tree-half passes through [64][36] ----
  if (wid < 8)
    *(float4*)(out_s + lane * OUT_LD + 4 * wid) = v;
  __syncthreads();
  {
    int col = tid & 31, rr = tid >> 5;
    #pragma unroll
    for (int k = 0; k < 2; ++k) {
      int row = rr + 32 * k;
      int gb = b0 + row, gt = t0 + col;
      if (gb < BATCH && gt < NUM_TREES)
        out[(size_t)gb * NUM_TREES + gt] = out_s[row * OUT_LD + col];
    }
  }
  __syncthreads();
  if (wid >= 8)
    *(float4*)(out_s + lane * OUT_LD + 4 * (wid - 8)) = v;
  __syncthreads();
  {
    int col = tid & 31, rr = tid >> 5;
    #pragma unroll
    for (int k = 0; k < 2; ++k) {
      int row = rr + 32 * k;
      int gb = b0 + row, gt = t0 + 32 + col;
      if (gb < BATCH && gt < NUM_TREES)
        out[(size_t)gb * NUM_TREES + gt] = out_s[row * OUT_LD + col];
    }
  }
}

// ================= fallback (no-ws path) =================
#define FB_BT 64
#define FB_TT 64
#define FB_TPR 16
#define FB_NROUNDS 4
#define FB_NTHREADS 1024
#define FB_XS (NFEAT * 64 * 4)
#define FB_NSU (FB_TPR * NUM_NODES)
#define FB_NS (FB_NSU * 8)
#define FB_OLD (FB_TT + 1)
#define FB_OS (FB_BT * FB_OLD * 4)
#define FB_SH (FB_XS + FB_NS + FB_OS)
#define FB_PREF ((FB_NSU + FB_NTHREADS - 1) / FB_NTHREADS)

__global__ __launch_bounds__(FB_NTHREADS, 1)
void fb_traverse(const float* __restrict__ x,
                 const float* __restrict__ thrg,
                 const int* __restrict__ featg,
                 const int* __restrict__ leftg,
                 const int* __restrict__ rightg,
                 const float* __restrict__ values,
                 float* __restrict__ out) {
  extern __shared__ unsigned char smem[];
  float* x_s     = (float*)smem;
  uint2* nodes_s = (uint2*)(smem + FB_XS);
  float* out_s   = (float*)(smem + FB_XS + FB_NS);
  const int tid = threadIdx.x, wid = tid >> 6, lane = tid & 63;
  const int b0 = blockIdx.y * FB_BT, t0 = blockIdx.x * FB_TT;
  uint2 pf[FB_PREF];
  auto load_round = [&](int rr) {
    const int gbase = (t0 + rr * FB_TPR) * NUM_NODES;
    #pragma unroll
    for (int k = 0; k < FB_PREF; ++k) {
      int fi = tid + k * FB_NTHREADS;
      uint2 v = make_uint2(0u, 0u);
      if (fi < FB_NSU) {
        int gi = gbase + fi;
        if (gi < FLAT_NODES) {
          uint32_t meta = (uint32_t)featg[gi] | ((uint32_t)leftg[gi] << 8) |
                          ((uint32_t)rightg[gi] << 20);
          v = make_uint2(__float_as_uint(thrg[gi]), meta);
        }
      }
      pf[k] = v;
    }
  };
  auto write_nodes = [&]() {
    #pragma unroll
    for (int k = 0; k < FB_PREF; ++k) {
      int fi = tid + k * FB_NTHREADS;
      if (fi < FB_NSU) nodes_s[fi] = pf[k];
    }
  };
  load_round(0);
  {
    const float4* xg = (const float4*)x;
    #pragma unroll
    for (int p = 0; p < (FB_BT * (NFEAT / 4)) / FB_NTHREADS; ++p) {
      int i = tid + p * FB_NTHREADS;
      int r = i >> 6, c = i & 63;
      int gb = b0 + r;
      float4 v = make_float4(0.f, 0.f, 0.f, 0.f);
      if (gb < BATCH) v = xg[gb * (NFEAT / 4) + c];
      int o = (c << 8) + (r ^ (c & 31));
      x_s[o] = v.x; x_s[o + 64] = v.y; x_s[o + 128] = v.z; x_s[o + 192] = v.w;
    }
  }
  write_nodes();
  __syncthreads();
  for (int r = 0; r < FB_NROUNDS; ++r) {
    if (r + 1 < FB_NROUNDS) load_round(r + 1);
    const uint2* nA = nodes_s + wid * NUM_NODES;
    const int tr0 = t0 + r * FB_TPR;
    const int gta = tr0 + wid;
    const int offA = (gta < NUM_TREES ? gta : 0) * NUM_NODES;
    uint2 na = nA[0];
    float va = 0.f;
    #pragma unroll
    for (int d = 0; d < DEPTH; ++d) {
      int fa = na.y & 0xFF;
      int la = (na.y >> 8) & 0xFFF;
      int ra = (int)(na.y >> 20);
      float xa = x_s[(fa << 6) + (lane ^ ((fa >> 2) & 31))];
      if (d < DEPTH - 1) {
        uint2 nla = nA[la], nra = nA[ra];
        na = (xa >= __uint_as_float(na.x)) ? nra : nla;
      } else {
        float vla = values[offA + la], vra = values[offA + ra];
        va = (xa >= __uint_as_float(na.x)) ? vra : vla;
      }
    }
    out_s[lane * FB_OLD + r * FB_TPR + wid] = va;
    __syncthreads();
    if (r + 1 < FB_NROUNDS) { write_nodes(); __syncthreads(); }
  }
  {
    const int gt = t0 + lane;
    #pragma unroll
    for (int p = 0; p < FB_BT / 16; ++p) {
      int rr = p * 16 + wid;
      int gb = b0 + rr;
      if (gb < BATCH && gt < NUM_TREES)
        out[gb * NUM_TREES + gt] = out_s[rr * FB_OLD + lane];
    }
  }
}

extern "C" void kernel_launch(void* const* d_in, const int* in_sizes, int n_in,
                              void* d_out, int out_size, void* d_ws, size_t ws_size,
                              hipStream_t stream) {
  const float* x          = (const float*)d_in[0];
  const float* thresholds = (const float*)d_in[1];
  const float* values     = (const float*)d_in[2];
  const int*   lefts      = (const int*)d_in[3];
  const int*   rights     = (const int*)d_in[4];
  const int*   features   = (const int*)d_in[5];
  float* out = (float*)d_out;

  if (ws_size >= WS_XT) {
    unsigned char* ws = (unsigned char*)d_ws;
    prepack_kernel<<<UNROLL_BLOCKS + TRANS_BLOCKS, 256, 0, stream>>>(
        thresholds, features, lefts, rights, values, x, ws);
    hipFuncSetAttribute(reinterpret_cast<const void*>(traverse64<true>),
                        hipFuncAttributeMaxDynamicSharedMemorySize, SH_BYTES);
    dim3 grid((NUM_TREES + TT - 1) / TT, (BATCH + BT - 1) / BT);   // 16 x 157
    traverse64<true><<<grid, NTHREADS, SH_BYTES, stream>>>(x, ws, out);
  } else if (ws_size >= WS_NEEDED) {
    unsigned char* ws = (unsigned char*)d_ws;
    prepack_kernel<<<UNROLL_BLOCKS, 256, 0, stream>>>(
        thresholds, features, lefts, rights, values, x, ws);
    hipFuncSetAttribute(reinterpret_cast<const void*>(traverse64<false>),
                        hipFuncAttributeMaxDynamicSharedMemorySize, SH_BYTES);
    dim3 grid((NUM_TREES + TT - 1) / TT, (BATCH + BT - 1) / BT);
    traverse64<false><<<grid, NTHREADS, SH_BYTES, stream>>>(x, ws, out);
  } else {
    hipFuncSetAttribute(reinterpret_cast<const void*>(fb_traverse),
                        hipFuncAttributeMaxDynamicSharedMemorySize, FB_SH);
    dim3 grid((NUM_TREES + FB_TT - 1) / FB_TT, (BATCH + FB_BT - 1) / FB_BT);
    fb_traverse<<<grid, FB_NTHREADS, FB_SH, stream>>>(
        x, thresholds, features, lefts, rights, values, out);
  }
}